// Round 1
// baseline (2929.840 us; speedup 1.0000x reference)
//
#include <hip/hip_runtime.h>
#include <math.h>

#define N_NODES 200000
#define N_EDGES 6400000
#define NEG_SLOPE 0.01f
#define EPS_F 1e-5f

__device__ __forceinline__ float sigmoidf_(float x) { return 1.0f / (1.0f + expf(-x)); }

// ---------------- K1: per-node GRU + x1_raw + stats1 (sum, sumsq per 9 ch) ----------------
__global__ void k_gru(const float* __restrict__ x,
                      const float* __restrict__ w_ih, const float* __restrict__ w_hh,
                      const float* __restrict__ b_ih, const float* __restrict__ b_hh,
                      float* __restrict__ x1_raw, float* __restrict__ stats1) {
    int i = blockIdx.x * blockDim.x + threadIdx.x;
    float vals[9];
    if (i < N_NODES) {
        float xv[5];
#pragma unroll
        for (int j = 0; j < 5; ++j) xv[j] = x[(size_t)i * 5 + j];
        float wih[6], whh[12], bih[6], bhh[6];
#pragma unroll
        for (int j = 0; j < 6; ++j) { wih[j] = w_ih[j]; bih[j] = b_ih[j]; bhh[j] = b_hh[j]; }
#pragma unroll
        for (int j = 0; j < 12; ++j) whh[j] = w_hh[j];
        float h0 = 0.f, h1 = 0.f;
#pragma unroll
        for (int t = 0; t < 4; ++t) {
            float xt = xv[t];
            float gi[6], gh[6];
#pragma unroll
            for (int j = 0; j < 6; ++j) {
                gi[j] = xt * wih[j] + bih[j];
                gh[j] = h0 * whh[2 * j] + h1 * whh[2 * j + 1] + bhh[j];
            }
            float r0 = sigmoidf_(gi[0] + gh[0]);
            float r1 = sigmoidf_(gi[1] + gh[1]);
            float z0 = sigmoidf_(gi[2] + gh[2]);
            float z1 = sigmoidf_(gi[3] + gh[3]);
            float n0 = tanhf(gi[4] + r0 * gh[4]);
            float n1 = tanhf(gi[5] + r1 * gh[5]);
            h0 = (1.f - z0) * n0 + z0 * h0;
            h1 = (1.f - z1) * n1 + z1 * h1;
            vals[2 * t] = h0;
            vals[2 * t + 1] = h1;
        }
        vals[8] = xv[4];
#pragma unroll
        for (int c = 0; c < 9; ++c) x1_raw[(size_t)i * 9 + c] = vals[c];
    } else {
#pragma unroll
        for (int c = 0; c < 9; ++c) vals[c] = 0.f;
    }
    __shared__ float sh[18];
    if (threadIdx.x < 18) sh[threadIdx.x] = 0.f;
    __syncthreads();
#pragma unroll
    for (int c = 0; c < 9; ++c) {
        float s = vals[c], q = vals[c] * vals[c];
#pragma unroll
        for (int off = 32; off > 0; off >>= 1) {
            s += __shfl_down(s, off, 64);
            q += __shfl_down(q, off, 64);
        }
        if ((threadIdx.x & 63) == 0) { atomicAdd(&sh[c], s); atomicAdd(&sh[9 + c], q); }
    }
    __syncthreads();
    if (threadIdx.x < 18) atomicAdd(&stats1[threadIdx.x], sh[threadIdx.x]);
}

// ---------------- K2: degree accumulation (edge part) ----------------
__global__ void k_deg(const int* __restrict__ col, const float* __restrict__ w,
                      float* __restrict__ deg) {
    int e = blockIdx.x * blockDim.x + threadIdx.x;
    if (e < N_EDGES) atomicAdd(&deg[col[e]], w[e]);
}

// ---------------- K3/K7: per-channel affine from stats ----------------
__global__ void k_norm_params(const float* __restrict__ stats, const float* __restrict__ gw,
                              const float* __restrict__ gb, const float* __restrict__ gms,
                              float* __restrict__ ab, int C) {
    int c = threadIdx.x;
    if (c < C) {
        float mean = stats[c] * (1.0f / N_NODES);
        float meansq = stats[C + c] * (1.0f / N_NODES);
        float ms = gms[c];
        float var = meansq - 2.f * ms * mean * mean + ms * ms * mean * mean;
        float alpha = gw[c] * rsqrtf(var + EPS_F);
        ab[c] = alpha;
        ab[C + c] = gb[c] - alpha * ms * mean;
    }
}

// ---------------- K4: norm1+leaky -> h = x1n @ W (9x8), hs = dinv*h, acc init ----------------
__global__ void k_x1_to_hs(const float* __restrict__ x1_raw, const float* __restrict__ ab1,
                           const float* __restrict__ gcn_w, const float* __restrict__ deg,
                           float* __restrict__ hs, float* __restrict__ acc,
                           float* __restrict__ dinv) {
    __shared__ float W[72];
    __shared__ float A[9], B[9];
    if (threadIdx.x < 72) W[threadIdx.x] = gcn_w[threadIdx.x];
    if (threadIdx.x < 9) { A[threadIdx.x] = ab1[threadIdx.x]; B[threadIdx.x] = ab1[9 + threadIdx.x]; }
    __syncthreads();
    int i = blockIdx.x * blockDim.x + threadIdx.x;
    if (i >= N_NODES) return;
    float v[9];
#pragma unroll
    for (int c = 0; c < 9; ++c) {
        float t = A[c] * x1_raw[(size_t)i * 9 + c] + B[c];
        v[c] = t >= 0.f ? t : NEG_SLOPE * t;
    }
    float di = rsqrtf(fmaxf(deg[i] + 1.0f, EPS_F));
    dinv[i] = di;
#pragma unroll
    for (int c = 0; c < 8; ++c) {
        float s = 0.f;
#pragma unroll
        for (int k = 0; k < 9; ++k) s += v[k] * W[k * 8 + c];
        s *= di;
        hs[(size_t)i * 8 + c] = s;
        acc[(size_t)i * 8 + c] = s;  // self-loop term dinv*h
    }
}

// ---------------- K5: edge scatter acc[col] += w * hs[row] ----------------
__global__ void k_scatter(const int* __restrict__ row, const int* __restrict__ col,
                          const float* __restrict__ ew, const float* __restrict__ hs,
                          float* __restrict__ acc) {
    int e = blockIdx.x * blockDim.x + threadIdx.x;
    if (e >= N_EDGES) return;
    int r = row[e], c = col[e];
    float w = ew[e];
    const float4* hp = (const float4*)(hs + (size_t)r * 8);
    float4 a = hp[0], b = hp[1];
    float* ap = acc + (size_t)c * 8;
    atomicAdd(ap + 0, w * a.x);
    atomicAdd(ap + 1, w * a.y);
    atomicAdd(ap + 2, w * a.z);
    atomicAdd(ap + 3, w * a.w);
    atomicAdd(ap + 4, w * b.x);
    atomicAdd(ap + 5, w * b.y);
    atomicAdd(ap + 6, w * b.z);
    atomicAdd(ap + 7, w * b.w);
}

// ---------------- K6: x2 = dinv*acc + gcn_b, stats2 ----------------
__global__ void k_x2_stats(const float* __restrict__ acc, const float* __restrict__ dinv,
                           const float* __restrict__ gcn_b, float* __restrict__ x2,
                           float* __restrict__ stats2) {
    int i = blockIdx.x * blockDim.x + threadIdx.x;
    float vals[8];
    if (i < N_NODES) {
        float di = dinv[i];
        float bb[8];
#pragma unroll
        for (int c = 0; c < 8; ++c) bb[c] = gcn_b[c];
#pragma unroll
        for (int c = 0; c < 8; ++c) {
            float t = di * acc[(size_t)i * 8 + c] + bb[c];
            vals[c] = t;
            x2[(size_t)i * 8 + c] = t;
        }
    } else {
#pragma unroll
        for (int c = 0; c < 8; ++c) vals[c] = 0.f;
    }
    __shared__ float sh[16];
    if (threadIdx.x < 16) sh[threadIdx.x] = 0.f;
    __syncthreads();
#pragma unroll
    for (int c = 0; c < 8; ++c) {
        float s = vals[c], q = vals[c] * vals[c];
#pragma unroll
        for (int off = 32; off > 0; off >>= 1) {
            s += __shfl_down(s, off, 64);
            q += __shfl_down(q, off, 64);
        }
        if ((threadIdx.x & 63) == 0) { atomicAdd(&sh[c], s); atomicAdd(&sh[8 + c], q); }
    }
    __syncthreads();
    if (threadIdx.x < 16) atomicAdd(&stats2[threadIdx.x], sh[threadIdx.x]);
}

// ---------------- K8: out = leaky(norm2(x2)) . fc_w + fc_b ----------------
__global__ void k_out(const float* __restrict__ x2, const float* __restrict__ ab2,
                      const float* __restrict__ fc_w, const float* __restrict__ fc_b,
                      float* __restrict__ out) {
    int i = blockIdx.x * blockDim.x + threadIdx.x;
    if (i >= N_NODES) return;
    float s = fc_b[0];
#pragma unroll
    for (int c = 0; c < 8; ++c) {
        float t = ab2[c] * x2[(size_t)i * 8 + c] + ab2[8 + c];
        t = t >= 0.f ? t : NEG_SLOPE * t;
        s += t * fc_w[c];
    }
    out[i] = s;
}

extern "C" void kernel_launch(void* const* d_in, const int* in_sizes, int n_in,
                              void* d_out, int out_size, void* d_ws, size_t ws_size,
                              hipStream_t stream) {
    const float* x = (const float*)d_in[0];
    const int* edge_index = (const int*)d_in[1];
    const float* edge_weight = (const float*)d_in[2];
    const float* gru_w_ih = (const float*)d_in[3];
    const float* gru_w_hh = (const float*)d_in[4];
    const float* gru_b_ih = (const float*)d_in[5];
    const float* gru_b_hh = (const float*)d_in[6];
    const float* gn1_w = (const float*)d_in[7];
    const float* gn1_b = (const float*)d_in[8];
    const float* gn1_ms = (const float*)d_in[9];
    const float* gn2_w = (const float*)d_in[10];
    const float* gn2_b = (const float*)d_in[11];
    const float* gn2_ms = (const float*)d_in[12];
    const float* gcn_w = (const float*)d_in[13];
    const float* gcn_b = (const float*)d_in[14];
    const float* fc_w = (const float*)d_in[15];
    const float* fc_b = (const float*)d_in[16];
    float* out = (float*)d_out;

    const int* e_row = edge_index;
    const int* e_col = edge_index + N_EDGES;

    // workspace layout (floats)
    float* ws = (float*)d_ws;
    const size_t N = N_NODES;
    float* stats1 = ws;            // 18
    float* stats2 = ws + 18;       // 16
    float* ab1 = ws + 36;          // 18
    float* ab2 = ws + 54;          // 16
    float* deg = ws + 72;          // N
    float* x1_raw = deg + N;       // 9N  (reused as x2)
    float* hs = x1_raw + 9 * N;    // 8N
    float* acc = hs + 8 * N;       // 8N
    float* dinv = acc + 8 * N;     // N
    float* x2 = x1_raw;            // reuse (x1_raw dead after K4)

    hipMemsetAsync(stats1, 0, 34 * sizeof(float), stream);
    hipMemsetAsync(deg, 0, N * sizeof(float), stream);

    const int BT = 256;
    int nblk = (N_NODES + BT - 1) / BT;
    int eblk = (N_EDGES + BT - 1) / BT;

    k_gru<<<nblk, BT, 0, stream>>>(x, gru_w_ih, gru_w_hh, gru_b_ih, gru_b_hh, x1_raw, stats1);
    k_deg<<<eblk, BT, 0, stream>>>(e_col, edge_weight, deg);
    k_norm_params<<<1, 32, 0, stream>>>(stats1, gn1_w, gn1_b, gn1_ms, ab1, 9);
    k_x1_to_hs<<<nblk, BT, 0, stream>>>(x1_raw, ab1, gcn_w, deg, hs, acc, dinv);
    k_scatter<<<eblk, BT, 0, stream>>>(e_row, e_col, edge_weight, hs, acc);
    k_x2_stats<<<nblk, BT, 0, stream>>>(acc, dinv, gcn_b, x2, stats2);
    k_norm_params<<<1, 32, 0, stream>>>(stats2, gn2_w, gn2_b, gn2_ms, ab2, 8);
    k_out<<<nblk, BT, 0, stream>>>(x2, ab2, fc_w, fc_b, out);
}

// Round 2
// 579.314 us; speedup vs baseline: 5.0574x; 5.0574x over previous
//
#include <hip/hip_runtime.h>
#include <math.h>

#define N_NODES 200000
#define N_EDGES 6400000
#define NEG_SLOPE 0.01f
#define EPS_F 1e-5f

// bucket partition params
#define BSHIFT 8
#define BSIZE 256                      // nodes per bucket
#define NBKT 782                       // ceil(N_NODES / BSIZE)
#define PCHUNK (256 * 96)              // edges per placement block
#define PBLK ((N_EDGES + PCHUNK - 1) / PCHUNK)

__device__ __forceinline__ float sigmoidf_(float x) { return 1.0f / (1.0f + expf(-x)); }

// ---------------- K1: per-node GRU + x1_raw + stats1 (sum, sumsq per 9 ch) ----------------
__global__ void k_gru(const float* __restrict__ x,
                      const float* __restrict__ w_ih, const float* __restrict__ w_hh,
                      const float* __restrict__ b_ih, const float* __restrict__ b_hh,
                      float* __restrict__ x1_raw, float* __restrict__ stats1) {
    int i = blockIdx.x * blockDim.x + threadIdx.x;
    float vals[9];
    if (i < N_NODES) {
        float xv[5];
#pragma unroll
        for (int j = 0; j < 5; ++j) xv[j] = x[(size_t)i * 5 + j];
        float wih[6], whh[12], bih[6], bhh[6];
#pragma unroll
        for (int j = 0; j < 6; ++j) { wih[j] = w_ih[j]; bih[j] = b_ih[j]; bhh[j] = b_hh[j]; }
#pragma unroll
        for (int j = 0; j < 12; ++j) whh[j] = w_hh[j];
        float h0 = 0.f, h1 = 0.f;
#pragma unroll
        for (int t = 0; t < 4; ++t) {
            float xt = xv[t];
            float gi[6], gh[6];
#pragma unroll
            for (int j = 0; j < 6; ++j) {
                gi[j] = xt * wih[j] + bih[j];
                gh[j] = h0 * whh[2 * j] + h1 * whh[2 * j + 1] + bhh[j];
            }
            float r0 = sigmoidf_(gi[0] + gh[0]);
            float r1 = sigmoidf_(gi[1] + gh[1]);
            float z0 = sigmoidf_(gi[2] + gh[2]);
            float z1 = sigmoidf_(gi[3] + gh[3]);
            float n0 = tanhf(gi[4] + r0 * gh[4]);
            float n1 = tanhf(gi[5] + r1 * gh[5]);
            h0 = (1.f - z0) * n0 + z0 * h0;
            h1 = (1.f - z1) * n1 + z1 * h1;
            vals[2 * t] = h0;
            vals[2 * t + 1] = h1;
        }
        vals[8] = xv[4];
#pragma unroll
        for (int c = 0; c < 9; ++c) x1_raw[(size_t)i * 9 + c] = vals[c];
    } else {
#pragma unroll
        for (int c = 0; c < 9; ++c) vals[c] = 0.f;
    }
    __shared__ float sh[18];
    if (threadIdx.x < 18) sh[threadIdx.x] = 0.f;
    __syncthreads();
#pragma unroll
    for (int c = 0; c < 9; ++c) {
        float s = vals[c], q = vals[c] * vals[c];
#pragma unroll
        for (int off = 32; off > 0; off >>= 1) {
            s += __shfl_down(s, off, 64);
            q += __shfl_down(q, off, 64);
        }
        if ((threadIdx.x & 63) == 0) { atomicAdd(&sh[c], s); atomicAdd(&sh[9 + c], q); }
    }
    __syncthreads();
    if (threadIdx.x < 18) atomicAdd(&stats1[threadIdx.x], sh[threadIdx.x]);
}

// ---------------- histogram of destination buckets ----------------
__global__ void k_hist(const int* __restrict__ col, unsigned* __restrict__ bcnt) {
    __shared__ unsigned cnt[NBKT];
    for (int i = threadIdx.x; i < NBKT; i += blockDim.x) cnt[i] = 0u;
    __syncthreads();
    int stride = gridDim.x * blockDim.x;
    for (int e = blockIdx.x * blockDim.x + threadIdx.x; e < N_EDGES; e += stride)
        atomicAdd(&cnt[col[e] >> BSHIFT], 1u);
    __syncthreads();
    for (int i = threadIdx.x; i < NBKT; i += blockDim.x)
        if (cnt[i]) atomicAdd(&bcnt[i], cnt[i]);
}

// ---------------- exclusive scan over NBKT bucket counts (1 block, 1024 thr) ----------------
__global__ void k_scan(const unsigned* __restrict__ bcnt, unsigned* __restrict__ boff,
                       unsigned* __restrict__ bcur) {
    __shared__ unsigned s0[1024];
    __shared__ unsigned s1[1024];
    int t = threadIdx.x;
    unsigned v = (t < NBKT) ? bcnt[t] : 0u;
    s0[t] = v;
    __syncthreads();
    unsigned* src = s0;
    unsigned* dst = s1;
    for (int d = 1; d < 1024; d <<= 1) {
        unsigned xv = src[t] + ((t >= d) ? src[t - d] : 0u);
        dst[t] = xv;
        __syncthreads();
        unsigned* tmp = src; src = dst; dst = tmp;
    }
    if (t < NBKT) { unsigned excl = src[t] - v; boff[t] = excl; bcur[t] = excl; }
    if (t == 0) boff[NBKT] = N_EDGES;
}

// ---------------- placement: partition edges into buckets, 8B packed records ----------------
// record: x = row | (local_col << 18), y = weight bits
__global__ void k_place(const int* __restrict__ row, const int* __restrict__ col,
                        const float* __restrict__ w,
                        unsigned* __restrict__ bcur, uint2* __restrict__ edata) {
    __shared__ unsigned cnt[NBKT];
    __shared__ unsigned cur[NBKT];
    for (int i = threadIdx.x; i < NBKT; i += blockDim.x) cnt[i] = 0u;
    __syncthreads();
    size_t base = (size_t)blockIdx.x * PCHUNK;
#pragma unroll 4
    for (int k = 0; k < 96; ++k) {
        size_t e = base + (size_t)k * 256 + threadIdx.x;
        if (e < N_EDGES) atomicAdd(&cnt[col[e] >> BSHIFT], 1u);
    }
    __syncthreads();
    for (int i = threadIdx.x; i < NBKT; i += blockDim.x) {
        unsigned c = cnt[i];
        cur[i] = c ? atomicAdd(&bcur[i], c) : 0u;
    }
    __syncthreads();
#pragma unroll 4
    for (int k = 0; k < 96; ++k) {
        size_t e = base + (size_t)k * 256 + threadIdx.x;
        if (e < N_EDGES) {
            int cc = col[e];
            int b = cc >> BSHIFT;
            unsigned pos = atomicAdd(&cur[b], 1u);
            uint2 rec;
            rec.x = (unsigned)row[e] | ((unsigned)(cc & (BSIZE - 1)) << 18);
            rec.y = __float_as_uint(w[e]);
            edata[pos] = rec;
        }
    }
}

// ---------------- per-bucket weighted degree -> dinv ----------------
__global__ void k_deg_b(const uint2* __restrict__ edata, const unsigned* __restrict__ boff,
                        float* __restrict__ dinv) {
    __shared__ float dw[BSIZE];
    int b = blockIdx.x;
    for (int i = threadIdx.x; i < BSIZE; i += 256) dw[i] = 0.f;
    __syncthreads();
    unsigned s = boff[b], epos = boff[b + 1];
    for (unsigned e = s + threadIdx.x; e < epos; e += 256) {
        uint2 d = edata[e];
        atomicAdd(&dw[(d.x >> 18) & (BSIZE - 1)], __uint_as_float(d.y));
    }
    __syncthreads();
    int nbase = b << BSHIFT;
    for (int i = threadIdx.x; i < BSIZE; i += 256) {
        int node = nbase + i;
        if (node < N_NODES) dinv[node] = rsqrtf(fmaxf(dw[i] + 1.0f, EPS_F));
    }
}

// ---------------- per-channel affine from stats ----------------
__global__ void k_norm_params(const float* __restrict__ stats, const float* __restrict__ gw,
                              const float* __restrict__ gb, const float* __restrict__ gms,
                              float* __restrict__ ab, int C) {
    int c = threadIdx.x;
    if (c < C) {
        float mean = stats[c] * (1.0f / N_NODES);
        float meansq = stats[C + c] * (1.0f / N_NODES);
        float ms = gms[c];
        float var = meansq - 2.f * ms * mean * mean + ms * ms * mean * mean;
        float alpha = gw[c] * rsqrtf(var + EPS_F);
        ab[c] = alpha;
        ab[C + c] = gb[c] - alpha * ms * mean;
    }
}

// ---------------- norm1+leaky -> h = x1n @ W (9x8), hs = dinv*h ----------------
__global__ void k_x1_to_hs(const float* __restrict__ x1_raw, const float* __restrict__ ab1,
                           const float* __restrict__ gcn_w, const float* __restrict__ dinv,
                           float* __restrict__ hs) {
    __shared__ float W[72];
    __shared__ float A[9], B[9];
    if (threadIdx.x < 72) W[threadIdx.x] = gcn_w[threadIdx.x];
    if (threadIdx.x < 9) { A[threadIdx.x] = ab1[threadIdx.x]; B[threadIdx.x] = ab1[9 + threadIdx.x]; }
    __syncthreads();
    int i = blockIdx.x * blockDim.x + threadIdx.x;
    if (i >= N_NODES) return;
    float v[9];
#pragma unroll
    for (int c = 0; c < 9; ++c) {
        float t = A[c] * x1_raw[(size_t)i * 9 + c] + B[c];
        v[c] = t >= 0.f ? t : NEG_SLOPE * t;
    }
    float di = dinv[i];
    float o[8];
#pragma unroll
    for (int c = 0; c < 8; ++c) {
        float s = 0.f;
#pragma unroll
        for (int k = 0; k < 9; ++k) s += v[k] * W[k * 8 + c];
        o[c] = s * di;
    }
    float4* hp = (float4*)(hs + (size_t)i * 8);
    hp[0] = make_float4(o[0], o[1], o[2], o[3]);
    hp[1] = make_float4(o[4], o[5], o[6], o[7]);
}

// ---------------- per-bucket accumulate: x2 = dinv*(sum + hs_self) + b, stats2 ----------------
__global__ void k_acc_b(const uint2* __restrict__ edata, const unsigned* __restrict__ boff,
                        const float* __restrict__ hs, const float* __restrict__ dinv,
                        const float* __restrict__ gcn_b,
                        float* __restrict__ x2, float* __restrict__ stats2) {
    __shared__ float accl[8 * BSIZE];  // SoA: accl[c*BSIZE + local] -> random banks
    __shared__ float sst[16];
    for (int i = threadIdx.x; i < 8 * BSIZE; i += 256) accl[i] = 0.f;
    if (threadIdx.x < 16) sst[threadIdx.x] = 0.f;
    __syncthreads();
    int b = blockIdx.x;
    unsigned s = boff[b], epos = boff[b + 1];
    for (unsigned e = s + threadIdx.x; e < epos; e += 256) {
        uint2 d = edata[e];
        int r = d.x & 0x3FFFF;
        int local = (d.x >> 18) & (BSIZE - 1);
        float w = __uint_as_float(d.y);
        const float4* hp = (const float4*)(hs + (size_t)r * 8);
        float4 a = hp[0], c4 = hp[1];
        atomicAdd(&accl[0 * BSIZE + local], w * a.x);
        atomicAdd(&accl[1 * BSIZE + local], w * a.y);
        atomicAdd(&accl[2 * BSIZE + local], w * a.z);
        atomicAdd(&accl[3 * BSIZE + local], w * a.w);
        atomicAdd(&accl[4 * BSIZE + local], w * c4.x);
        atomicAdd(&accl[5 * BSIZE + local], w * c4.y);
        atomicAdd(&accl[6 * BSIZE + local], w * c4.z);
        atomicAdd(&accl[7 * BSIZE + local], w * c4.w);
    }
    __syncthreads();
    int nbase = b << BSHIFT;
    float ls[8], lq[8];
#pragma unroll
    for (int c = 0; c < 8; ++c) { ls[c] = 0.f; lq[c] = 0.f; }
    {
        int i = threadIdx.x;  // BSIZE == blockDim.x
        int node = nbase + i;
        if (node < N_NODES) {
            float di = dinv[node];
            const float4* hp = (const float4*)(hs + (size_t)node * 8);
            float4 a = hp[0], c4 = hp[1];
            float self[8] = {a.x, a.y, a.z, a.w, c4.x, c4.y, c4.z, c4.w};
            float o[8];
#pragma unroll
            for (int c = 0; c < 8; ++c) {
                float t = di * (accl[c * BSIZE + i] + self[c]) + gcn_b[c];
                o[c] = t;
                ls[c] += t;
                lq[c] += t * t;
            }
            float4* xp = (float4*)(x2 + (size_t)node * 8);
            xp[0] = make_float4(o[0], o[1], o[2], o[3]);
            xp[1] = make_float4(o[4], o[5], o[6], o[7]);
        }
    }
#pragma unroll
    for (int c = 0; c < 8; ++c) {
        float sv = ls[c], qv = lq[c];
#pragma unroll
        for (int off = 32; off > 0; off >>= 1) {
            sv += __shfl_down(sv, off, 64);
            qv += __shfl_down(qv, off, 64);
        }
        if ((threadIdx.x & 63) == 0) { atomicAdd(&sst[c], sv); atomicAdd(&sst[8 + c], qv); }
    }
    __syncthreads();
    if (threadIdx.x < 16) atomicAdd(&stats2[threadIdx.x], sst[threadIdx.x]);
}

// ---------------- out = leaky(norm2(x2)) . fc_w + fc_b ----------------
__global__ void k_out(const float* __restrict__ x2, const float* __restrict__ ab2,
                      const float* __restrict__ fc_w, const float* __restrict__ fc_b,
                      float* __restrict__ out) {
    int i = blockIdx.x * blockDim.x + threadIdx.x;
    if (i >= N_NODES) return;
    float s = fc_b[0];
#pragma unroll
    for (int c = 0; c < 8; ++c) {
        float t = ab2[c] * x2[(size_t)i * 8 + c] + ab2[8 + c];
        t = t >= 0.f ? t : NEG_SLOPE * t;
        s += t * fc_w[c];
    }
    out[i] = s;
}

// =================== fallback (small-ws) path: r1 atomic scatter ===================
__global__ void f_deg(const int* __restrict__ col, const float* __restrict__ w,
                      float* __restrict__ deg) {
    int e = blockIdx.x * blockDim.x + threadIdx.x;
    if (e < N_EDGES) atomicAdd(&deg[col[e]], w[e]);
}
__global__ void f_dinv(const float* __restrict__ deg, float* __restrict__ dinv) {
    int i = blockIdx.x * blockDim.x + threadIdx.x;
    if (i < N_NODES) dinv[i] = rsqrtf(fmaxf(deg[i] + 1.0f, EPS_F));
}
__global__ void f_scatter(const int* __restrict__ row, const int* __restrict__ col,
                          const float* __restrict__ ew, const float* __restrict__ hs,
                          float* __restrict__ acc) {
    int e = blockIdx.x * blockDim.x + threadIdx.x;
    if (e >= N_EDGES) return;
    int r = row[e], c = col[e];
    float w = ew[e];
    const float4* hp = (const float4*)(hs + (size_t)r * 8);
    float4 a = hp[0], b = hp[1];
    float* ap = acc + (size_t)c * 8;
    atomicAdd(ap + 0, w * a.x);
    atomicAdd(ap + 1, w * a.y);
    atomicAdd(ap + 2, w * a.z);
    atomicAdd(ap + 3, w * a.w);
    atomicAdd(ap + 4, w * b.x);
    atomicAdd(ap + 5, w * b.y);
    atomicAdd(ap + 6, w * b.z);
    atomicAdd(ap + 7, w * b.w);
}
__global__ void f_x2_stats(const float* __restrict__ acc, const float* __restrict__ dinv,
                           const float* __restrict__ gcn_b, float* __restrict__ x2,
                           float* __restrict__ stats2) {
    int i = blockIdx.x * blockDim.x + threadIdx.x;
    float vals[8];
    if (i < N_NODES) {
        float di = dinv[i];
#pragma unroll
        for (int c = 0; c < 8; ++c) {
            float t = di * acc[(size_t)i * 8 + c] + gcn_b[c];
            vals[c] = t;
            x2[(size_t)i * 8 + c] = t;
        }
    } else {
#pragma unroll
        for (int c = 0; c < 8; ++c) vals[c] = 0.f;
    }
    __shared__ float sh[16];
    if (threadIdx.x < 16) sh[threadIdx.x] = 0.f;
    __syncthreads();
#pragma unroll
    for (int c = 0; c < 8; ++c) {
        float s = vals[c], q = vals[c] * vals[c];
#pragma unroll
        for (int off = 32; off > 0; off >>= 1) {
            s += __shfl_down(s, off, 64);
            q += __shfl_down(q, off, 64);
        }
        if ((threadIdx.x & 63) == 0) { atomicAdd(&sh[c], s); atomicAdd(&sh[8 + c], q); }
    }
    __syncthreads();
    if (threadIdx.x < 16) atomicAdd(&stats2[threadIdx.x], sh[threadIdx.x]);
}

extern "C" void kernel_launch(void* const* d_in, const int* in_sizes, int n_in,
                              void* d_out, int out_size, void* d_ws, size_t ws_size,
                              hipStream_t stream) {
    const float* x = (const float*)d_in[0];
    const int* edge_index = (const int*)d_in[1];
    const float* edge_weight = (const float*)d_in[2];
    const float* gru_w_ih = (const float*)d_in[3];
    const float* gru_w_hh = (const float*)d_in[4];
    const float* gru_b_ih = (const float*)d_in[5];
    const float* gru_b_hh = (const float*)d_in[6];
    const float* gn1_w = (const float*)d_in[7];
    const float* gn1_b = (const float*)d_in[8];
    const float* gn1_ms = (const float*)d_in[9];
    const float* gn2_w = (const float*)d_in[10];
    const float* gn2_b = (const float*)d_in[11];
    const float* gn2_ms = (const float*)d_in[12];
    const float* gcn_w = (const float*)d_in[13];
    const float* gcn_b = (const float*)d_in[14];
    const float* fc_w = (const float*)d_in[15];
    const float* fc_b = (const float*)d_in[16];
    float* out = (float*)d_out;

    const int* e_row = edge_index;
    const int* e_col = edge_index + N_EDGES;

    float* ws = (float*)d_ws;
    const size_t N = N_NODES;
    const int BT = 256;
    const int nblk = (N_NODES + BT - 1) / BT;

    // header words: [0..18) stats1, [18..34) stats2, [34..52) ab1, [52..68) ab2,
    // [68..68+NBKT) bcnt, then boff (NBKT+1), then bcur (NBKT); pad to even.
    const size_t HOFF_BCNT = 68;
    const size_t HOFF_BOFF = HOFF_BCNT + NBKT;
    const size_t HOFF_BCUR = HOFF_BOFF + NBKT + 1;
    size_t hdr = HOFF_BCUR + NBKT;
    hdr = (hdr + 1) & ~(size_t)1;  // 8B-align what follows

    const size_t need = (hdr + N /*dinv*/ + 9 * N /*x1_raw*/ + 8 * N /*hs*/) * 4
                        + (size_t)N_EDGES * 8 /*edata*/;

    float* stats1 = ws;
    float* stats2 = ws + 18;
    float* ab1 = ws + 34;
    float* ab2 = ws + 52;

    if (ws_size >= need) {
        unsigned* bcnt = (unsigned*)(ws + HOFF_BCNT);
        unsigned* boff = (unsigned*)(ws + HOFF_BOFF);
        unsigned* bcur = (unsigned*)(ws + HOFF_BCUR);
        float* dinv = ws + hdr;
        float* x1_raw = dinv + N;
        float* hs = x1_raw + 9 * N;
        uint2* edata = (uint2*)(hs + 8 * N);
        float* x2 = x1_raw;  // reuse (x1_raw dead after k_x1_to_hs)

        // zero stats + bcnt
        hipMemsetAsync(ws, 0, (HOFF_BCNT + NBKT) * sizeof(float), stream);

        k_gru<<<nblk, BT, 0, stream>>>(x, gru_w_ih, gru_w_hh, gru_b_ih, gru_b_hh, x1_raw, stats1);
        k_hist<<<1024, BT, 0, stream>>>(e_col, bcnt);
        k_scan<<<1, 1024, 0, stream>>>(bcnt, boff, bcur);
        k_place<<<PBLK, BT, 0, stream>>>(e_row, e_col, edge_weight, bcur, edata);
        k_deg_b<<<NBKT, BT, 0, stream>>>(edata, boff, dinv);
        k_norm_params<<<1, 32, 0, stream>>>(stats1, gn1_w, gn1_b, gn1_ms, ab1, 9);
        k_x1_to_hs<<<nblk, BT, 0, stream>>>(x1_raw, ab1, gcn_w, dinv, hs);
        k_acc_b<<<NBKT, BT, 0, stream>>>(edata, boff, hs, dinv, gcn_b, x2, stats2);
        k_norm_params<<<1, 32, 0, stream>>>(stats2, gn2_w, gn2_b, gn2_ms, ab2, 8);
        k_out<<<nblk, BT, 0, stream>>>(x2, ab2, fc_w, fc_b, out);
    } else {
        // fallback: r1-style atomic scatter (needs 26N+68 floats)
        float* deg = ws + 68;
        float* dinv = deg;  // deg converted in-place is unsafe; use separate region below
        float* x1_raw = ws + 68 + N;
        float* hs = x1_raw + 9 * N;
        float* acc = hs + 8 * N;
        float* dinv2 = acc + 8 * N;
        float* x2 = x1_raw;
        (void)dinv;

        hipMemsetAsync(ws, 0, (68 + N) * sizeof(float), stream);

        const int eblk = (N_EDGES + BT - 1) / BT;
        k_gru<<<nblk, BT, 0, stream>>>(x, gru_w_ih, gru_w_hh, gru_b_ih, gru_b_hh, x1_raw, stats1);
        f_deg<<<eblk, BT, 0, stream>>>(e_col, edge_weight, deg);
        f_dinv<<<nblk, BT, 0, stream>>>(deg, dinv2);
        k_norm_params<<<1, 32, 0, stream>>>(stats1, gn1_w, gn1_b, gn1_ms, ab1, 9);
        k_x1_to_hs<<<nblk, BT, 0, stream>>>(x1_raw, ab1, gcn_w, dinv2, hs);
        hipMemcpyAsync(acc, hs, 8 * N * sizeof(float), hipMemcpyDeviceToDevice, stream);
        f_scatter<<<eblk, BT, 0, stream>>>(e_row, e_col, edge_weight, hs, acc);
        f_x2_stats<<<nblk, BT, 0, stream>>>(acc, dinv2, gcn_b, x2, stats2);
        k_norm_params<<<1, 32, 0, stream>>>(stats2, gn2_w, gn2_b, gn2_ms, ab2, 8);
        k_out<<<nblk, BT, 0, stream>>>(x2, ab2, fc_w, fc_b, out);
    }
}

// Round 3
// 503.885 us; speedup vs baseline: 5.8145x; 1.1497x over previous
//
#include <hip/hip_runtime.h>
#include <math.h>

#define N_NODES 200000
#define N_EDGES 6400000
#define NEG_SLOPE 0.01f
#define EPS_F 1e-5f

// bucket partition params
#define BSHIFT 8
#define BSIZE 256                      // nodes per bucket
#define NBKT 782                       // ceil(N_NODES / BSIZE)
#define SACC 4                         // splits per bucket for acc/deg
#define PCHUNK 8192                    // edges per placement block
#define PBLK ((N_EDGES + PCHUNK - 1) / PCHUNK)   // 782

__device__ __forceinline__ float sigmoidf_(float x) { return 1.0f / (1.0f + expf(-x)); }

// ---------------- K1: per-node GRU + x1_raw + stats1 (sum, sumsq per 9 ch) ----------------
__global__ void k_gru(const float* __restrict__ x,
                      const float* __restrict__ w_ih, const float* __restrict__ w_hh,
                      const float* __restrict__ b_ih, const float* __restrict__ b_hh,
                      float* __restrict__ x1_raw, float* __restrict__ stats1) {
    int i = blockIdx.x * blockDim.x + threadIdx.x;
    float vals[9];
    if (i < N_NODES) {
        float xv[5];
#pragma unroll
        for (int j = 0; j < 5; ++j) xv[j] = x[(size_t)i * 5 + j];
        float wih[6], whh[12], bih[6], bhh[6];
#pragma unroll
        for (int j = 0; j < 6; ++j) { wih[j] = w_ih[j]; bih[j] = b_ih[j]; bhh[j] = b_hh[j]; }
#pragma unroll
        for (int j = 0; j < 12; ++j) whh[j] = w_hh[j];
        float h0 = 0.f, h1 = 0.f;
#pragma unroll
        for (int t = 0; t < 4; ++t) {
            float xt = xv[t];
            float gi[6], gh[6];
#pragma unroll
            for (int j = 0; j < 6; ++j) {
                gi[j] = xt * wih[j] + bih[j];
                gh[j] = h0 * whh[2 * j] + h1 * whh[2 * j + 1] + bhh[j];
            }
            float r0 = sigmoidf_(gi[0] + gh[0]);
            float r1 = sigmoidf_(gi[1] + gh[1]);
            float z0 = sigmoidf_(gi[2] + gh[2]);
            float z1 = sigmoidf_(gi[3] + gh[3]);
            float n0 = tanhf(gi[4] + r0 * gh[4]);
            float n1 = tanhf(gi[5] + r1 * gh[5]);
            h0 = (1.f - z0) * n0 + z0 * h0;
            h1 = (1.f - z1) * n1 + z1 * h1;
            vals[2 * t] = h0;
            vals[2 * t + 1] = h1;
        }
        vals[8] = xv[4];
#pragma unroll
        for (int c = 0; c < 9; ++c) x1_raw[(size_t)i * 9 + c] = vals[c];
    } else {
#pragma unroll
        for (int c = 0; c < 9; ++c) vals[c] = 0.f;
    }
    __shared__ float sh[18];
    if (threadIdx.x < 18) sh[threadIdx.x] = 0.f;
    __syncthreads();
#pragma unroll
    for (int c = 0; c < 9; ++c) {
        float s = vals[c], q = vals[c] * vals[c];
#pragma unroll
        for (int off = 32; off > 0; off >>= 1) {
            s += __shfl_down(s, off, 64);
            q += __shfl_down(q, off, 64);
        }
        if ((threadIdx.x & 63) == 0) { atomicAdd(&sh[c], s); atomicAdd(&sh[9 + c], q); }
    }
    __syncthreads();
    if (threadIdx.x < 18) atomicAdd(&stats1[threadIdx.x], sh[threadIdx.x]);
}

// ---------------- histogram of destination buckets (padded counters, stride 8) -------------
__global__ void k_hist(const int* __restrict__ col, unsigned* __restrict__ bcnt) {
    __shared__ unsigned cnt[NBKT];
    for (int i = threadIdx.x; i < NBKT; i += blockDim.x) cnt[i] = 0u;
    __syncthreads();
    const int4* c4 = (const int4*)col;
    int stride = gridDim.x * blockDim.x;
    for (int i = blockIdx.x * blockDim.x + threadIdx.x; i < N_EDGES / 4; i += stride) {
        int4 v = c4[i];
        atomicAdd(&cnt[v.x >> BSHIFT], 1u);
        atomicAdd(&cnt[v.y >> BSHIFT], 1u);
        atomicAdd(&cnt[v.z >> BSHIFT], 1u);
        atomicAdd(&cnt[v.w >> BSHIFT], 1u);
    }
    __syncthreads();
    for (int i = threadIdx.x; i < NBKT; i += blockDim.x)
        if (cnt[i]) atomicAdd(&bcnt[(size_t)i * 8], cnt[i]);
}

// ---------------- exclusive scan over NBKT bucket counts (1 block, 1024 thr) ----------------
__global__ void k_scan(const unsigned* __restrict__ bcnt, unsigned* __restrict__ boff,
                       unsigned* __restrict__ bcur) {
    __shared__ unsigned s0[1024];
    __shared__ unsigned s1[1024];
    int t = threadIdx.x;
    unsigned v = (t < NBKT) ? bcnt[(size_t)t * 8] : 0u;
    s0[t] = v;
    __syncthreads();
    unsigned* src = s0;
    unsigned* dst = s1;
    for (int d = 1; d < 1024; d <<= 1) {
        unsigned xv = src[t] + ((t >= d) ? src[t - d] : 0u);
        dst[t] = xv;
        __syncthreads();
        unsigned* tmp = src; src = dst; dst = tmp;
    }
    if (t < NBKT) { unsigned excl = src[t] - v; boff[t] = excl; bcur[(size_t)t * 8] = excl; }
    if (t == 0) boff[NBKT] = N_EDGES;
}

// ---------------- placement: partition edges into buckets, 8B packed records ----------------
// record: x = row | (local_col << 18), y = weight bits
__global__ void k_place(const int* __restrict__ row, const int* __restrict__ col,
                        const float* __restrict__ w,
                        unsigned* __restrict__ bcur, uint2* __restrict__ edata) {
    __shared__ unsigned cnt[NBKT];
    __shared__ unsigned cur[NBKT];
    for (int i = threadIdx.x; i < NBKT; i += blockDim.x) cnt[i] = 0u;
    __syncthreads();
    const size_t base = (size_t)blockIdx.x * PCHUNK;
    int colr[32];
#pragma unroll
    for (int k = 0; k < 32; ++k) {
        size_t e = base + (size_t)k * 256 + threadIdx.x;
        colr[k] = (e < N_EDGES) ? col[e] : -1;
        if (colr[k] >= 0) atomicAdd(&cnt[colr[k] >> BSHIFT], 1u);
    }
    __syncthreads();
    for (int i = threadIdx.x; i < NBKT; i += blockDim.x) {
        unsigned c = cnt[i];
        cur[i] = c ? atomicAdd(&bcur[(size_t)i * 8], c) : 0u;
    }
    __syncthreads();
#pragma unroll
    for (int k = 0; k < 32; ++k) {
        size_t e = base + (size_t)k * 256 + threadIdx.x;
        if (e < N_EDGES) {
            int cc = colr[k];
            int b = cc >> BSHIFT;
            unsigned pos = atomicAdd(&cur[b], 1u);
            uint2 rec;
            rec.x = (unsigned)row[e] | ((unsigned)(cc & (BSIZE - 1)) << 18);
            rec.y = __float_as_uint(w[e]);
            edata[pos] = rec;
        }
    }
}

// ---------------- per-bucket weighted degree (4-way split) -> deg (atomic combine) ----------
__global__ void k_deg_split(const uint2* __restrict__ edata, const unsigned* __restrict__ boff,
                            float* __restrict__ deg) {
    __shared__ float dw[BSIZE];
    int b = blockIdx.x >> 2;
    int s = blockIdx.x & 3;
    if (threadIdx.x < BSIZE) dw[threadIdx.x] = 0.f;
    __syncthreads();
    unsigned e0 = boff[b], e1 = boff[b + 1];
    unsigned n = e1 - e0;
    unsigned a = e0 + (n * (unsigned)s) / 4u;
    unsigned bnd = e0 + (n * (unsigned)(s + 1)) / 4u;
    for (unsigned e = a + threadIdx.x; e < bnd; e += 256) {
        uint2 d = edata[e];
        atomicAdd(&dw[(d.x >> 18) & (BSIZE - 1)], __uint_as_float(d.y));
    }
    __syncthreads();
    int node = (b << BSHIFT) + threadIdx.x;
    if (threadIdx.x < BSIZE && node < N_NODES) {
        float v = dw[threadIdx.x];
        if (v != 0.f) atomicAdd(&deg[node], v);
    }
}

// ---------------- per-channel affine from stats ----------------
__global__ void k_norm_params(const float* __restrict__ stats, const float* __restrict__ gw,
                              const float* __restrict__ gb, const float* __restrict__ gms,
                              float* __restrict__ ab, int C) {
    int c = threadIdx.x;
    if (c < C) {
        float mean = stats[c] * (1.0f / N_NODES);
        float meansq = stats[C + c] * (1.0f / N_NODES);
        float ms = gms[c];
        float var = meansq - 2.f * ms * mean * mean + ms * ms * mean * mean;
        float alpha = gw[c] * rsqrtf(var + EPS_F);
        ab[c] = alpha;
        ab[C + c] = gb[c] - alpha * ms * mean;
    }
}

// ---------------- norm1+leaky -> h = x1n @ W (9x8), hs = dinv*h ----------------
__global__ void k_x1_to_hs(const float* __restrict__ x1_raw, const float* __restrict__ ab1,
                           const float* __restrict__ gcn_w, const float* __restrict__ deg,
                           float* __restrict__ hs) {
    __shared__ float W[72];
    __shared__ float A[9], B[9];
    if (threadIdx.x < 72) W[threadIdx.x] = gcn_w[threadIdx.x];
    if (threadIdx.x < 9) { A[threadIdx.x] = ab1[threadIdx.x]; B[threadIdx.x] = ab1[9 + threadIdx.x]; }
    __syncthreads();
    int i = blockIdx.x * blockDim.x + threadIdx.x;
    if (i >= N_NODES) return;
    float v[9];
#pragma unroll
    for (int c = 0; c < 9; ++c) {
        float t = A[c] * x1_raw[(size_t)i * 9 + c] + B[c];
        v[c] = t >= 0.f ? t : NEG_SLOPE * t;
    }
    float di = rsqrtf(fmaxf(deg[i] + 1.0f, EPS_F));
    float o[8];
#pragma unroll
    for (int c = 0; c < 8; ++c) {
        float s = 0.f;
#pragma unroll
        for (int k = 0; k < 9; ++k) s += v[k] * W[k * 8 + c];
        o[c] = s * di;
    }
    float4* hp = (float4*)(hs + (size_t)i * 8);
    hp[0] = make_float4(o[0], o[1], o[2], o[3]);
    hp[1] = make_float4(o[4], o[5], o[6], o[7]);
}

// ---------------- 4-way split accumulate into per-split partial tiles (non-atomic out) ------
__global__ void k_acc_split(const uint2* __restrict__ edata, const unsigned* __restrict__ boff,
                            const float* __restrict__ hs, float* __restrict__ partials) {
    __shared__ float accl[8 * BSIZE];  // SoA: accl[c*BSIZE + local]
    int b = blockIdx.x >> 2;
    int s = blockIdx.x & 3;
    for (int i = threadIdx.x; i < 8 * BSIZE; i += 256) accl[i] = 0.f;
    __syncthreads();
    unsigned e0 = boff[b], e1 = boff[b + 1];
    unsigned n = e1 - e0;
    unsigned a = e0 + (n * (unsigned)s) / 4u;
    unsigned bnd = e0 + (n * (unsigned)(s + 1)) / 4u;
    for (unsigned e = a + threadIdx.x; e < bnd; e += 256) {
        uint2 d = edata[e];
        int r = d.x & 0x3FFFF;
        int local = (d.x >> 18) & (BSIZE - 1);
        float w = __uint_as_float(d.y);
        const float4* hp = (const float4*)(hs + (size_t)r * 8);
        float4 aa = hp[0], cc = hp[1];
        atomicAdd(&accl[0 * BSIZE + local], w * aa.x);
        atomicAdd(&accl[1 * BSIZE + local], w * aa.y);
        atomicAdd(&accl[2 * BSIZE + local], w * aa.z);
        atomicAdd(&accl[3 * BSIZE + local], w * aa.w);
        atomicAdd(&accl[4 * BSIZE + local], w * cc.x);
        atomicAdd(&accl[5 * BSIZE + local], w * cc.y);
        atomicAdd(&accl[6 * BSIZE + local], w * cc.z);
        atomicAdd(&accl[7 * BSIZE + local], w * cc.w);
    }
    __syncthreads();
    size_t p = (size_t)blockIdx.x * (8 * BSIZE);
    for (int i = threadIdx.x; i < 8 * BSIZE; i += 256) partials[p + i] = accl[i];
}

// ---------------- combine partials + self loop -> x2, stats2 ----------------
__global__ void k_combine(const float* __restrict__ partials, const float* __restrict__ hs,
                          const float* __restrict__ deg, const float* __restrict__ gcn_b,
                          float* __restrict__ x2, float* __restrict__ stats2) {
    __shared__ float sst[16];
    if (threadIdx.x < 16) sst[threadIdx.x] = 0.f;
    __syncthreads();
    int b = blockIdx.x;
    int tid = threadIdx.x;
    int node = (b << BSHIFT) + tid;
    float ls[8], lq[8];
#pragma unroll
    for (int c = 0; c < 8; ++c) { ls[c] = 0.f; lq[c] = 0.f; }
    if (node < N_NODES) {
        size_t pb = (size_t)b * 4 * (8 * BSIZE);
        float acc[8];
#pragma unroll
        for (int c = 0; c < 8; ++c) acc[c] = 0.f;
#pragma unroll
        for (int s = 0; s < 4; ++s) {
#pragma unroll
            for (int c = 0; c < 8; ++c)
                acc[c] += partials[pb + (size_t)s * (8 * BSIZE) + c * BSIZE + tid];
        }
        float di = rsqrtf(fmaxf(deg[node] + 1.0f, EPS_F));
        const float4* hp = (const float4*)(hs + (size_t)node * 8);
        float4 a = hp[0], c4 = hp[1];
        float self[8] = {a.x, a.y, a.z, a.w, c4.x, c4.y, c4.z, c4.w};
        float o[8];
#pragma unroll
        for (int c = 0; c < 8; ++c) {
            float t = di * (acc[c] + self[c]) + gcn_b[c];
            o[c] = t;
            ls[c] = t;
            lq[c] = t * t;
        }
        float4* xp = (float4*)(x2 + (size_t)node * 8);
        xp[0] = make_float4(o[0], o[1], o[2], o[3]);
        xp[1] = make_float4(o[4], o[5], o[6], o[7]);
    }
#pragma unroll
    for (int c = 0; c < 8; ++c) {
        float sv = ls[c], qv = lq[c];
#pragma unroll
        for (int off = 32; off > 0; off >>= 1) {
            sv += __shfl_down(sv, off, 64);
            qv += __shfl_down(qv, off, 64);
        }
        if ((threadIdx.x & 63) == 0) { atomicAdd(&sst[c], sv); atomicAdd(&sst[8 + c], qv); }
    }
    __syncthreads();
    if (threadIdx.x < 16) atomicAdd(&stats2[threadIdx.x], sst[threadIdx.x]);
}

// ---------------- out = leaky(norm2(x2)) . fc_w + fc_b ----------------
__global__ void k_out(const float* __restrict__ x2, const float* __restrict__ ab2,
                      const float* __restrict__ fc_w, const float* __restrict__ fc_b,
                      float* __restrict__ out) {
    int i = blockIdx.x * blockDim.x + threadIdx.x;
    if (i >= N_NODES) return;
    float s = fc_b[0];
#pragma unroll
    for (int c = 0; c < 8; ++c) {
        float t = ab2[c] * x2[(size_t)i * 8 + c] + ab2[8 + c];
        t = t >= 0.f ? t : NEG_SLOPE * t;
        s += t * fc_w[c];
    }
    out[i] = s;
}

// ---------------- tier2: single block per bucket (r2 structure, recompute dinv) -------------
__global__ void k_deg_b2(const uint2* __restrict__ edata, const unsigned* __restrict__ boff,
                         float* __restrict__ deg) {
    __shared__ float dw[BSIZE];
    int b = blockIdx.x;
    if (threadIdx.x < BSIZE) dw[threadIdx.x] = 0.f;
    __syncthreads();
    unsigned s = boff[b], epos = boff[b + 1];
    for (unsigned e = s + threadIdx.x; e < epos; e += 256) {
        uint2 d = edata[e];
        atomicAdd(&dw[(d.x >> 18) & (BSIZE - 1)], __uint_as_float(d.y));
    }
    __syncthreads();
    int node = (b << BSHIFT) + threadIdx.x;
    if (threadIdx.x < BSIZE && node < N_NODES) deg[node] = dw[threadIdx.x];
}

__global__ void k_acc_b2(const uint2* __restrict__ edata, const unsigned* __restrict__ boff,
                         const float* __restrict__ hs, const float* __restrict__ deg,
                         const float* __restrict__ gcn_b,
                         float* __restrict__ x2, float* __restrict__ stats2) {
    __shared__ float accl[8 * BSIZE];
    __shared__ float sst[16];
    for (int i = threadIdx.x; i < 8 * BSIZE; i += 256) accl[i] = 0.f;
    if (threadIdx.x < 16) sst[threadIdx.x] = 0.f;
    __syncthreads();
    int b = blockIdx.x;
    unsigned s = boff[b], epos = boff[b + 1];
    for (unsigned e = s + threadIdx.x; e < epos; e += 256) {
        uint2 d = edata[e];
        int r = d.x & 0x3FFFF;
        int local = (d.x >> 18) & (BSIZE - 1);
        float w = __uint_as_float(d.y);
        const float4* hp = (const float4*)(hs + (size_t)r * 8);
        float4 a = hp[0], c4 = hp[1];
        atomicAdd(&accl[0 * BSIZE + local], w * a.x);
        atomicAdd(&accl[1 * BSIZE + local], w * a.y);
        atomicAdd(&accl[2 * BSIZE + local], w * a.z);
        atomicAdd(&accl[3 * BSIZE + local], w * a.w);
        atomicAdd(&accl[4 * BSIZE + local], w * c4.x);
        atomicAdd(&accl[5 * BSIZE + local], w * c4.y);
        atomicAdd(&accl[6 * BSIZE + local], w * c4.z);
        atomicAdd(&accl[7 * BSIZE + local], w * c4.w);
    }
    __syncthreads();
    int nbase = b << BSHIFT;
    float ls[8], lq[8];
#pragma unroll
    for (int c = 0; c < 8; ++c) { ls[c] = 0.f; lq[c] = 0.f; }
    {
        int i = threadIdx.x;
        int node = nbase + i;
        if (node < N_NODES) {
            float di = rsqrtf(fmaxf(deg[node] + 1.0f, EPS_F));
            const float4* hp = (const float4*)(hs + (size_t)node * 8);
            float4 a = hp[0], c4 = hp[1];
            float self[8] = {a.x, a.y, a.z, a.w, c4.x, c4.y, c4.z, c4.w};
            float o[8];
#pragma unroll
            for (int c = 0; c < 8; ++c) {
                float t = di * (accl[c * BSIZE + i] + self[c]) + gcn_b[c];
                o[c] = t;
                ls[c] += t;
                lq[c] += t * t;
            }
            float4* xp = (float4*)(x2 + (size_t)node * 8);
            xp[0] = make_float4(o[0], o[1], o[2], o[3]);
            xp[1] = make_float4(o[4], o[5], o[6], o[7]);
        }
    }
#pragma unroll
    for (int c = 0; c < 8; ++c) {
        float sv = ls[c], qv = lq[c];
#pragma unroll
        for (int off = 32; off > 0; off >>= 1) {
            sv += __shfl_down(sv, off, 64);
            qv += __shfl_down(qv, off, 64);
        }
        if ((threadIdx.x & 63) == 0) { atomicAdd(&sst[c], sv); atomicAdd(&sst[8 + c], qv); }
    }
    __syncthreads();
    if (threadIdx.x < 16) atomicAdd(&stats2[threadIdx.x], sst[threadIdx.x]);
}

// =================== tier3 (small-ws) path: r1 atomic scatter ===================
__global__ void f_deg(const int* __restrict__ col, const float* __restrict__ w,
                      float* __restrict__ deg) {
    int e = blockIdx.x * blockDim.x + threadIdx.x;
    if (e < N_EDGES) atomicAdd(&deg[col[e]], w[e]);
}
__global__ void f_scatter(const int* __restrict__ row, const int* __restrict__ col,
                          const float* __restrict__ ew, const float* __restrict__ hs,
                          float* __restrict__ acc) {
    int e = blockIdx.x * blockDim.x + threadIdx.x;
    if (e >= N_EDGES) return;
    int r = row[e], c = col[e];
    float w = ew[e];
    const float4* hp = (const float4*)(hs + (size_t)r * 8);
    float4 a = hp[0], b = hp[1];
    float* ap = acc + (size_t)c * 8;
    atomicAdd(ap + 0, w * a.x);
    atomicAdd(ap + 1, w * a.y);
    atomicAdd(ap + 2, w * a.z);
    atomicAdd(ap + 3, w * a.w);
    atomicAdd(ap + 4, w * b.x);
    atomicAdd(ap + 5, w * b.y);
    atomicAdd(ap + 6, w * b.z);
    atomicAdd(ap + 7, w * b.w);
}
__global__ void f_x2_stats(const float* __restrict__ acc, const float* __restrict__ deg,
                           const float* __restrict__ gcn_b, float* __restrict__ x2,
                           float* __restrict__ stats2) {
    int i = blockIdx.x * blockDim.x + threadIdx.x;
    float vals[8];
    if (i < N_NODES) {
        float di = rsqrtf(fmaxf(deg[i] + 1.0f, EPS_F));
#pragma unroll
        for (int c = 0; c < 8; ++c) {
            float t = di * acc[(size_t)i * 8 + c] + gcn_b[c];
            vals[c] = t;
            x2[(size_t)i * 8 + c] = t;
        }
    } else {
#pragma unroll
        for (int c = 0; c < 8; ++c) vals[c] = 0.f;
    }
    __shared__ float sh[16];
    if (threadIdx.x < 16) sh[threadIdx.x] = 0.f;
    __syncthreads();
#pragma unroll
    for (int c = 0; c < 8; ++c) {
        float s = vals[c], q = vals[c] * vals[c];
#pragma unroll
        for (int off = 32; off > 0; off >>= 1) {
            s += __shfl_down(s, off, 64);
            q += __shfl_down(q, off, 64);
        }
        if ((threadIdx.x & 63) == 0) { atomicAdd(&sh[c], s); atomicAdd(&sh[8 + c], q); }
    }
    __syncthreads();
    if (threadIdx.x < 16) atomicAdd(&stats2[threadIdx.x], sh[threadIdx.x]);
}

extern "C" void kernel_launch(void* const* d_in, const int* in_sizes, int n_in,
                              void* d_out, int out_size, void* d_ws, size_t ws_size,
                              hipStream_t stream) {
    const float* x = (const float*)d_in[0];
    const int* edge_index = (const int*)d_in[1];
    const float* edge_weight = (const float*)d_in[2];
    const float* gru_w_ih = (const float*)d_in[3];
    const float* gru_w_hh = (const float*)d_in[4];
    const float* gru_b_ih = (const float*)d_in[5];
    const float* gru_b_hh = (const float*)d_in[6];
    const float* gn1_w = (const float*)d_in[7];
    const float* gn1_b = (const float*)d_in[8];
    const float* gn1_ms = (const float*)d_in[9];
    const float* gn2_w = (const float*)d_in[10];
    const float* gn2_b = (const float*)d_in[11];
    const float* gn2_ms = (const float*)d_in[12];
    const float* gcn_w = (const float*)d_in[13];
    const float* gcn_b = (const float*)d_in[14];
    const float* fc_w = (const float*)d_in[15];
    const float* fc_b = (const float*)d_in[16];
    float* out = (float*)d_out;

    const int* e_row = edge_index;
    const int* e_col = edge_index + N_EDGES;

    float* ws = (float*)d_ws;
    const size_t N = N_NODES;
    const int BT = 256;
    const int nblk = (N_NODES + BT - 1) / BT;

    // layout (words): stats1[0..18) stats2[18..34) ab1[34..52) ab2[52..68)
    // bcnt_pad[68 .. 68+NBKT*8) boff[.. +NBKT+1) bcur_pad[.. +NBKT*8), pad even,
    // deg[N], x1_raw[9N] (reused as x2), hs[8N], edata[2*E words], partials[SACC*NBKT*2048]
    const size_t HOFF_BCNT = 68;
    const size_t HOFF_BOFF = HOFF_BCNT + (size_t)NBKT * 8;
    const size_t HOFF_BCUR = HOFF_BOFF + NBKT + 1;
    size_t hdr = HOFF_BCUR + (size_t)NBKT * 8;
    hdr = (hdr + 1) & ~(size_t)1;

    const size_t OFF_DEG = hdr;
    const size_t OFF_X1 = OFF_DEG + N;
    const size_t OFF_HS = OFF_X1 + 9 * N;
    const size_t OFF_ED = OFF_HS + 8 * N;                 // even ✓
    const size_t OFF_PART = OFF_ED + (size_t)N_EDGES * 2;
    const size_t need1 = (OFF_PART + (size_t)SACC * NBKT * 8 * BSIZE) * 4;
    const size_t need2 = OFF_PART * 4;

    float* stats1 = ws;
    float* stats2 = ws + 18;
    float* ab1 = ws + 34;
    float* ab2 = ws + 52;

    if (ws_size >= need2) {
        unsigned* bcnt = (unsigned*)(ws + HOFF_BCNT);
        unsigned* boff = (unsigned*)(ws + HOFF_BOFF);
        unsigned* bcur = (unsigned*)(ws + HOFF_BCUR);
        float* deg = ws + OFF_DEG;
        float* x1_raw = ws + OFF_X1;
        float* hs = ws + OFF_HS;
        uint2* edata = (uint2*)(ws + OFF_ED);
        float* partials = ws + OFF_PART;
        float* x2 = x1_raw;  // x1_raw dead after k_x1_to_hs

        hipMemsetAsync(ws, 0, HOFF_BOFF * sizeof(float), stream);           // stats+ab+bcnt
        hipMemsetAsync(deg, 0, N * sizeof(float), stream);

        k_gru<<<nblk, BT, 0, stream>>>(x, gru_w_ih, gru_w_hh, gru_b_ih, gru_b_hh, x1_raw, stats1);
        k_hist<<<256, BT, 0, stream>>>(e_col, bcnt);
        k_scan<<<1, 1024, 0, stream>>>(bcnt, boff, bcur);
        k_place<<<PBLK, BT, 0, stream>>>(e_row, e_col, edge_weight, bcur, edata);
        k_norm_params<<<1, 32, 0, stream>>>(stats1, gn1_w, gn1_b, gn1_ms, ab1, 9);
        if (ws_size >= need1) {
            k_deg_split<<<NBKT * SACC, BT, 0, stream>>>(edata, boff, deg);
            k_x1_to_hs<<<nblk, BT, 0, stream>>>(x1_raw, ab1, gcn_w, deg, hs);
            k_acc_split<<<NBKT * SACC, BT, 0, stream>>>(edata, boff, hs, partials);
            k_combine<<<NBKT, BT, 0, stream>>>(partials, hs, deg, gcn_b, x2, stats2);
        } else {
            k_deg_b2<<<NBKT, BT, 0, stream>>>(edata, boff, deg);
            k_x1_to_hs<<<nblk, BT, 0, stream>>>(x1_raw, ab1, gcn_w, deg, hs);
            k_acc_b2<<<NBKT, BT, 0, stream>>>(edata, boff, hs, deg, gcn_b, x2, stats2);
        }
        k_norm_params<<<1, 32, 0, stream>>>(stats2, gn2_w, gn2_b, gn2_ms, ab2, 8);
        k_out<<<nblk, BT, 0, stream>>>(x2, ab2, fc_w, fc_b, out);
    } else {
        // tier3: r1-style atomic scatter (needs ~26N floats)
        float* deg = ws + 68;
        float* x1_raw = deg + N;
        float* hs = x1_raw + 9 * N;
        float* acc = hs + 8 * N;
        float* x2 = x1_raw;

        hipMemsetAsync(ws, 0, (68 + N) * sizeof(float), stream);

        const int eblk = (N_EDGES + BT - 1) / BT;
        k_gru<<<nblk, BT, 0, stream>>>(x, gru_w_ih, gru_w_hh, gru_b_ih, gru_b_hh, x1_raw, stats1);
        f_deg<<<eblk, BT, 0, stream>>>(e_col, edge_weight, deg);
        k_norm_params<<<1, 32, 0, stream>>>(stats1, gn1_w, gn1_b, gn1_ms, ab1, 9);
        k_x1_to_hs<<<nblk, BT, 0, stream>>>(x1_raw, ab1, gcn_w, deg, hs);
        hipMemcpyAsync(acc, hs, 8 * N * sizeof(float), hipMemcpyDeviceToDevice, stream);
        f_scatter<<<eblk, BT, 0, stream>>>(e_row, e_col, edge_weight, hs, acc);
        f_x2_stats<<<nblk, BT, 0, stream>>>(acc, deg, gcn_b, x2, stats2);
        k_norm_params<<<1, 32, 0, stream>>>(stats2, gn2_w, gn2_b, gn2_ms, ab2, 8);
        k_out<<<nblk, BT, 0, stream>>>(x2, ab2, fc_w, fc_b, out);
    }
}